// Round 1
// baseline (358.510 us; speedup 1.0000x reference)
//
#include <hip/hip_runtime.h>
#include <hip/hip_bf16.h>

#define K_TOP 10
#define PS 7
#define HD 4
#define QN 4096
#define TN 4
#define CN 64
#define HN 256
#define WN 256
#define K0 15
#define CH 16            // CN / HD
#define SP (PS * PS)     // 49
#define OUT_PER_Q (SP * CN)  // 3136

__global__ __launch_bounds__(256) void wpsum_kernel(
    const float* __restrict__ vid,
    const float* __restrict__ dists,
    const int*   __restrict__ inds,
    float*       __restrict__ out)
{
    __shared__ float s_w[HD][K_TOP];
    __shared__ int   s_base[HD][K_TOP];
    __shared__ float s_acc[CN][SP + 1];   // 64 x 50 f32 = 12.8 KB, padded

    const int q = blockIdx.x;
    const int t = threadIdx.x;

    // Stage weights and precomputed gather base offsets for all 4 heads x 10 k.
    if (t < HD * K_TOP) {
        const int h = t / K_TOP;
        const int k = t - h * K_TOP;
        const int idx = (h * QN + q) * K0 + k;
        s_w[h][k] = dists[idx];
        const int tt = inds[idx * 3 + 0];
        const int ii = inds[idx * 3 + 1];
        const int jj = inds[idx * 3 + 2];
        s_base[h][k] = ((tt * CN + h * CH) * HN + ii) * WN + jj;
    }
    __syncthreads();

    // Each thread accumulates ~12.25 output elements, ordered e = c_all*49 + s
    // so a wave's lanes read mostly-contiguous vid addresses (runs of 7 floats).
    for (int e = t; e < OUT_PER_Q; e += 256) {
        const int c_all = e / SP;        // 0..63  (h*16 + c)
        const int s     = e - c_all * SP; // 0..48
        const int h  = c_all >> 4;
        const int c  = c_all & 15;
        const int pi = s / PS;
        const int pj = s - pi * PS;
        const int off = c * (HN * WN) + pi * WN + pj;
        float acc = 0.f;
        #pragma unroll
        for (int k = 0; k < K_TOP; ++k) {
            acc = fmaf(s_w[h][k], vid[s_base[h][k] + off], acc);
        }
        s_acc[c_all][s] = acc;
    }
    __syncthreads();

    // Coalesced store in output-native order: out[q*3136 + s*64 + c_all].
    float* outq = out + q * OUT_PER_Q;
    for (int e = t; e < OUT_PER_Q; e += 256) {
        const int s     = e >> 6;   // e = s*64 + c_all
        const int c_all = e & 63;
        outq[e] = s_acc[c_all][s];
    }
}

extern "C" void kernel_launch(void* const* d_in, const int* in_sizes, int n_in,
                              void* d_out, int out_size, void* d_ws, size_t ws_size,
                              hipStream_t stream) {
    const float* vid   = (const float*)d_in[0];
    const float* dists = (const float*)d_in[1];
    const int*   inds  = (const int*)d_in[2];
    float* out = (float*)d_out;

    wpsum_kernel<<<QN, 256, 0, stream>>>(vid, dists, inds, out);
}